// Round 4
// baseline (141.458 us; speedup 1.0000x reference)
//
#include <hip/hip_runtime.h>
#include <hip/hip_fp16.h>

#define Bsz 256
#define Nn  1152
#define Kk  10
#define NT  384      // 6 waves
#define NW  6

#define W_ELEMS (Kk*Nn*128)   // 2949120
#define U_ELEMS (Bsz*Nn*8)    // 2359296

__device__ __forceinline__ unsigned pkh2(float x, float y) {
    __half2 h = __floats2half2_rn(x, y);
    return *reinterpret_cast<unsigned*>(&h);
}
__device__ __forceinline__ float2 uph2(unsigned v) {
    __half2 h;
    *reinterpret_cast<unsigned*>(&h) = v;
    return __half22float2(h);
}
__device__ __forceinline__ void up8(const uint4 q, float f[8]) {
    float2 a = uph2(q.x), b = uph2(q.y), c = uph2(q.z), d = uph2(q.w);
    f[0]=a.x; f[1]=a.y; f[2]=b.x; f[3]=b.y; f[4]=c.x; f[5]=c.y; f[6]=d.x; f[7]=d.y;
}

// fp32 -> fp16 conversion of W then u into workspace (8 elems/thread)
__global__ void cvt_kernel(const float* __restrict__ W, const float* __restrict__ u,
                           __half2* __restrict__ Wh, __half2* __restrict__ uh) {
    const int idx = blockIdx.x * blockDim.x + threadIdx.x;
    const int wg = W_ELEMS / 8;
    const float4* p;
    __half2* o;
    if (idx < wg) {
        p = (const float4*)W + (size_t)idx * 2;
        o = Wh + (size_t)idx * 4;
    } else {
        const int j = idx - wg;
        p = (const float4*)u + (size_t)j * 2;
        o = uh + (size_t)j * 4;
    }
    const float4 a = p[0], b = p[1];
    o[0] = __floats2half2_rn(a.x, a.y);
    o[1] = __floats2half2_rn(a.z, a.w);
    o[2] = __floats2half2_rn(b.x, b.y);
    o[3] = __floats2half2_rn(b.z, b.w);
}

// One block per (b, k); 6 waves; u_hat fp16 in LDS layout uhS[n*8 + j]
// (half2 of o-pair j). ~39.7 KB LDS -> 4 blocks/CU.
// it=0 s-pass is fused into phase 1 (fp32 partial sums + parity shuffle-reduce).
template<bool HALF>
__global__ __launch_bounds__(NT, 6)
void digitcaps_kernel(const float* __restrict__ u32, const float* __restrict__ W32,
                      const __half* __restrict__ uh, const __half* __restrict__ Wh,
                      float* __restrict__ out)
{
    const int t    = threadIdx.x;
    const int lane = t & 63;
    const int wav  = t >> 6;
    const int b    = blockIdx.x;     // 0..255
    const int k    = blockIdx.y;     // 0..9

    __shared__ unsigned uhS[Nn * 8];     // 36864 B
    __shared__ __half   cS[Nn];          // 2304 B  unnormalized e per n
    __shared__ float    redS[NW * 17];   // 408 B   [wav][16 s-cols + d]; also max scratch [0..5]
    __shared__ __align__(16) float vS[16];
    __shared__ float    mS;

    // ---------------- Phase 1: u_hat = u . W, fused it0 s-partials ----------
    {
        const int oh   = t & 1;      // o-half
        const int nsub = t >> 1;     // 0..191
        float sacc[8];
        #pragma unroll
        for (int o = 0; o < 8; ++o) sacc[o] = 0.f;
        for (int r = 0; r < 6; ++r) {
            const int n = r * 192 + nsub;
            float ua[8];
            if (HALF) {
                up8(*(const uint4*)(uh + ((size_t)b * Nn + n) * 8), ua);
            } else {
                const float4* up = (const float4*)(u32 + ((size_t)b * Nn + n) * 8);
                const float4 x0 = up[0], x1 = up[1];
                ua[0]=x0.x; ua[1]=x0.y; ua[2]=x0.z; ua[3]=x0.w;
                ua[4]=x1.x; ua[5]=x1.y; ua[6]=x1.z; ua[7]=x1.w;
            }
            float a0[8];
            #pragma unroll
            for (int o = 0; o < 8; ++o) a0[o] = 0.f;
            #pragma unroll
            for (int i = 0; i < 8; ++i) {
                float wv[8];
                if (HALF) {
                    up8(*(const uint4*)(Wh + ((size_t)(k * Nn + n)) * 128 + i * 16 + oh * 8), wv);
                } else {
                    const float4* wp = (const float4*)(W32 + ((size_t)k * Nn + n) * 128 + i * 16 + oh * 8);
                    const float4 w0 = wp[0], w1 = wp[1];
                    wv[0]=w0.x; wv[1]=w0.y; wv[2]=w0.z; wv[3]=w0.w;
                    wv[4]=w1.x; wv[5]=w1.y; wv[6]=w1.z; wv[7]=w1.w;
                }
                const float x = ua[i];
                #pragma unroll
                for (int o = 0; o < 8; ++o) a0[o] += x * wv[o];
            }
            *(uint4*)&uhS[n * 8 + oh * 4] =
                make_uint4(pkh2(a0[0], a0[1]), pkh2(a0[2], a0[3]),
                           pkh2(a0[4], a0[5]), pkh2(a0[6], a0[7]));
            #pragma unroll
            for (int o = 0; o < 8; ++o) sacc[o] += a0[o];
        }
        // reduce sacc over lanes of same parity (oh preserved)
        #pragma unroll
        for (int off = 2; off <= 32; off <<= 1)
            #pragma unroll
            for (int o = 0; o < 8; ++o) sacc[o] += __shfl_xor(sacc[o], off);
        if (lane < 2) {
            #pragma unroll
            for (int o = 0; o < 8; ++o) redS[wav * 17 + lane * 8 + o] = sacc[o];
        }
    }
    __syncthreads();

    // ---------------- Phase 2: routing ----------------
    float lg[3] = {0.f, 0.f, 0.f};
    float v0[16];
    const int j_s = lane & 7;
    const int g_s = lane >> 3;

    for (int it = 0; it < 3; ++it) {
        if (it > 0) {
            // broadcast v
            const float4* vp = (const float4*)vS;
            #pragma unroll
            for (int q4 = 0; q4 < 4; ++q4) *(float4*)&v0[4*q4] = vp[q4];
            // a-scan: rows n = t, t+384, t+768
            #pragma unroll
            for (int r = 0; r < 3; ++r) {
                const int n = t + r * NT;
                float fa[8], fb[8];
                up8(*(const uint4*)&uhS[n * 8], fa);
                up8(*(const uint4*)&uhS[n * 8 + 4], fb);
                float acc = 0.f;
                #pragma unroll
                for (int o = 0; o < 8; ++o) acc += fa[o] * v0[o] + fb[o] * v0[8 + o];
                lg[r] += acc;
            }
            // block max
            float m = fmaxf(fmaxf(lg[0], lg[1]), lg[2]);
            #pragma unroll
            for (int off = 1; off <= 32; off <<= 1) m = fmaxf(m, __shfl_xor(m, off));
            if (lane == 0) redS[wav] = m;
            __syncthreads();
            if (t == 0) {
                float mm = redS[0];
                for (int w = 1; w < NW; ++w) mm = fmaxf(mm, redS[w]);
                mS = mm;
            }
            __syncthreads();
            m = mS;
            cS[t]          = __float2half(__expf(lg[0] - m));
            cS[t + NT]     = __float2half(__expf(lg[1] - m));
            cS[t + 2*NT]   = __float2half(__expf(lg[2] - m));
            __syncthreads();
            // s-scan: numerator + denominator
            float spx = 0.f, spy = 0.f, dp = 0.f;
            #pragma unroll
            for (int cc = 0; cc < 24; ++cc) {
                const int n = cc * 48 + wav * 8 + g_s;
                const float c = __half2float(cS[n]);
                const float2 f = uph2(uhS[n * 8 + j_s]);
                spx += c * f.x; spy += c * f.y; dp += c;
            }
            #pragma unroll
            for (int off = 8; off <= 32; off <<= 1) {
                spx += __shfl_xor(spx, off);
                spy += __shfl_xor(spy, off);
                dp  += __shfl_xor(dp,  off);
            }
            if (lane < 8) {
                redS[wav * 17 + 2*j_s    ] = spx;
                redS[wav * 17 + 2*j_s + 1] = spy;
            }
            if (lane == 0) redS[wav * 17 + 16] = dp;
            __syncthreads();
        }

        // ---- squash (16 lanes of wave 0) ----
        if (t < 16) {
            float s = 0.f;
            #pragma unroll
            for (int w = 0; w < NW; ++w) s += redS[w * 17 + t];
            float d;
            if (it == 0) d = (float)Nn;
            else {
                d = 0.f;
                #pragma unroll
                for (int w = 0; w < NW; ++w) d += redS[w * 17 + 16];
            }
            s /= d;
            float s2 = s * s;
            #pragma unroll
            for (int off = 1; off <= 8; off <<= 1) s2 += __shfl_xor(s2, off);
            const float scale = (s2 / (1.f + s2)) * rsqrtf(fmaxf(s2, 1e-30f));
            const float v = s * scale;
            vS[t] = v;
            if (it == 2) out[((size_t)k * Bsz + b) * 16 + t] = v;
        }
        __syncthreads();
    }
}

extern "C" void kernel_launch(void* const* d_in, const int* in_sizes, int n_in,
                              void* d_out, int out_size, void* d_ws, size_t ws_size,
                              hipStream_t stream) {
    const float* u = (const float*)d_in[0];
    const float* W = (const float*)d_in[1];
    float* out = (float*)d_out;
    const size_t need = (size_t)(W_ELEMS + U_ELEMS) * sizeof(__half);
    if (ws_size >= need) {
        __half* Wh = (__half*)d_ws;
        __half* uhp = (__half*)((char*)d_ws + (size_t)W_ELEMS * sizeof(__half));
        cvt_kernel<<<dim3((W_ELEMS + U_ELEMS) / 8 / 256), dim3(256), 0, stream>>>(
            W, u, (__half2*)Wh, (__half2*)uhp);
        digitcaps_kernel<true><<<dim3(Bsz, Kk), dim3(NT), 0, stream>>>(
            nullptr, nullptr, uhp, Wh, out);
    } else {
        digitcaps_kernel<false><<<dim3(Bsz, Kk), dim3(NT), 0, stream>>>(
            u, W, nullptr, nullptr, out);
    }
}